// Round 11
// baseline (917.535 us; speedup 1.0000x reference)
//
#include <hip/hip_runtime.h>

typedef __bf16 bf16;
typedef __bf16 bf16x8 __attribute__((ext_vector_type(8)));
typedef float f32x4 __attribute__((ext_vector_type(4)));

#define NTOK 16384
#define DMODEL 1024
#define HFFN 4096
#define NEXP 8
#define CAP 2048

#define VMCNT0() asm volatile("s_waitcnt vmcnt(0)" ::: "memory")
#define BARRIER() __builtin_amdgcn_s_barrier()
#define PRIO1() __builtin_amdgcn_s_setprio(1)
#define PRIO0() __builtin_amdgcn_s_setprio(0)

__device__ __forceinline__ void gload16(const void* g, void* l) {
  __builtin_amdgcn_global_load_lds((const __attribute__((address_space(1))) void*)g,
                                   (__attribute__((address_space(3))) void*)l, 16, 0, 0);
}

// exact tanh-approx gelu via sigmoid identity
__device__ __forceinline__ float gelu_f(float v) {
  float t = v * v;
  float s2 = v * fmaf(0.10294358f, t, 2.3022084f);
  float e = __builtin_exp2f(-s2);
  return v * __builtin_amdgcn_rcpf(1.0f + e);
}

__device__ __forceinline__ void xcd_remap(int& bx, int& by) {
  const int gx = gridDim.x;
  const int lg = 31 - __clz((unsigned)gx);
  const int w = blockIdx.x + gx * blockIdx.y;
  bx = (w >> 3) & (gx - 1);
  by = (w & 7) | (((w >> 3) >> lg) << 3);
}

// ---------------- x: f32 -> bf16 ----------------
__global__ __launch_bounds__(256) void cvt_x_kernel(const float* __restrict__ x,
                                                    bf16* __restrict__ xb) {
  int i = blockIdx.x * blockDim.x + threadIdx.x;
  const float4* a = (const float4*)x + (size_t)i * 2;
  float4 v0 = a[0], v1 = a[1];
  bf16x8 o;
  o[0]=(bf16)v0.x; o[1]=(bf16)v0.y; o[2]=(bf16)v0.z; o[3]=(bf16)v0.w;
  o[4]=(bf16)v1.x; o[5]=(bf16)v1.y; o[6]=(bf16)v1.z; o[7]=(bf16)v1.w;
  *(bf16x8*)(xb + (size_t)i * 8) = o;
}

// ---------------- router ----------------
__global__ __launch_bounds__(64) void router_kernel(const float* __restrict__ x,
                                                    const float* __restrict__ gw,
                                                    float* __restrict__ probs) {
  int t = blockIdx.x;
  int l = threadIdx.x;
  int e = l & 7, chunk = l >> 3;
  const float* xr = x + (size_t)t * DMODEL + chunk * 128;
  const float* gwr = gw + (size_t)(chunk * 128) * NEXP + e;
  float a0 = 0.f, a1 = 0.f;
  #pragma unroll
  for (int d = 0; d < 128; d += 8) {
    float4 xv = *(const float4*)(xr + d);
    float4 xw = *(const float4*)(xr + d + 4);
    a0 += xv.x * gwr[(d+0)*8] + xv.y * gwr[(d+1)*8] + xv.z * gwr[(d+2)*8] + xv.w * gwr[(d+3)*8];
    a1 += xw.x * gwr[(d+4)*8] + xw.y * gwr[(d+5)*8] + xw.z * gwr[(d+6)*8] + xw.w * gwr[(d+7)*8];
  }
  float acc = a0 + a1;
  acc += __shfl_xor(acc, 8);
  acc += __shfl_xor(acc, 16);
  acc += __shfl_xor(acc, 32);
  float m = acc;
  m = fmaxf(m, __shfl_xor(m, 1));
  m = fmaxf(m, __shfl_xor(m, 2));
  m = fmaxf(m, __shfl_xor(m, 4));
  float ex = expf(acc - m);
  float s = ex;
  s += __shfl_xor(s, 1); s += __shfl_xor(s, 2); s += __shfl_xor(s, 4);
  if (l < 8) probs[(size_t)e * NTOK + t] = ex / s;
}

// ---------------- per-expert top-2048 radix select ----------------
__global__ __launch_bounds__(256) void topk_kernel(const float* __restrict__ probs,
                                                   int* __restrict__ oidx,
                                                   float* __restrict__ oscr) {
  const int e = blockIdx.x;
  const float* p = probs + (size_t)e * NTOK;
  const int t = threadIdx.x;
  __shared__ unsigned hist[256];
  __shared__ unsigned sg[256], sq[256];
  __shared__ unsigned bcast[4];
  unsigned pref = 0, krem = CAP;
  for (int pass = 0; pass < 4; ++pass) {
    const int sh = 24 - pass * 8;
    hist[t] = 0;
    __syncthreads();
    for (int j = 0; j < 64; ++j) {
      unsigned u = __float_as_uint(p[t * 64 + j]);
      bool ok = (pass == 0) || ((u >> (sh + 8)) == pref);
      if (ok) atomicAdd(&hist[(u >> sh) & 255u], 1u);
    }
    __syncthreads();
    if (t == 0) {
      unsigned cum = 0; int b = 255;
      for (; b > 0; --b) {
        unsigned c = hist[b];
        if (cum + c >= krem) break;
        cum += c;
      }
      bcast[0] = (pref << 8) | (unsigned)b;
      bcast[1] = krem - cum;
    }
    __syncthreads();
    pref = bcast[0];
    krem = bcast[1];
  }
  const unsigned thr = pref;
  const unsigned neq_take = krem;
  unsigned cgt = 0, ceq = 0;
  for (int j = 0; j < 64; ++j) {
    unsigned u = __float_as_uint(p[t * 64 + j]);
    cgt += (u > thr);
    ceq += (u == thr);
  }
  sg[t] = cgt; sq[t] = ceq;
  __syncthreads();
  if (t == 0) {
    unsigned ag = 0, aq = 0;
    for (int i = 0; i < 256; ++i) {
      unsigned g = sg[i], q = sq[i];
      sg[i] = ag; sq[i] = aq;
      ag += g; aq += q;
    }
    bcast[2] = ag;
  }
  __syncthreads();
  const unsigned ngt = bcast[2];
  unsigned og = sg[t], oq = sq[t];
  int* oi = oidx + e * CAP;
  float* os = oscr + e * CAP;
  for (int j = 0; j < 64; ++j) {
    int tok = t * 64 + j;
    float pv = p[tok];
    unsigned u = __float_as_uint(pv);
    if (u > thr) {
      oi[og] = tok; os[og] = pv; ++og;
    } else if (u == thr) {
      if (oq < neq_take) { oi[ngt + oq] = tok; os[ngt + oq] = pv; }
      ++oq;
    }
  }
}

// ---------------- weight transpose + cvt ----------------
__global__ __launch_bounds__(256) void transpose_cvt(const float* __restrict__ in_e,
                                                     const float* __restrict__ in_s,
                                                     bf16* __restrict__ outp,
                                                     int R, int C) {
  int z = blockIdx.z;
  const float* in = (z < 8) ? (in_e + (size_t)z * (size_t)R * C) : in_s;
  bf16* out = outp + (size_t)z * (size_t)R * C;
  __shared__ float tile[64][65];
  int tx = threadIdx.x & 63, ty = threadIdx.x >> 6;
  int c0 = blockIdx.x * 64, r0 = blockIdx.y * 64;
  #pragma unroll
  for (int j = 0; j < 16; ++j) {
    int r = ty + j * 4;
    tile[r][tx] = in[(size_t)(r0 + r) * C + c0 + tx];
  }
  __syncthreads();
  #pragma unroll
  for (int j = 0; j < 16; ++j) {
    int c = ty + j * 4;
    out[(size_t)(c0 + c) * R + r0 + tx] = (bf16)tile[tx][c];
  }
}

// =====================================================================
// Occupancy-first GEMM: 128x256 tile, BK=32, 512 thr (8 waves 2x4,
// per-wave 64x64), 2 LDS buffers x 24KB = 48KB -> 2 blocks/CU
// (launch_bounds(512,4): VGPR<=128). Each SIMD: 4 waves from 2
// INDEPENDENT blocks -> cross-block TLP hides barrier/wait bubbles
// (m97/m114 mechanism). Minimal-sync K-loop, 1 barrier + 1 vmcnt(0)
// per K-tile, zero sched fences:
//   iter t: read frags from buf[t&1]; stage(t+1)->buf[(t+1)&1];
//           16 MFMA; VMCNT(0); BARRIER.
// Safety: stage(t+1) targets the buffer whose tile-(t-1) reads were
// consumed by MFMA(t-1) before BARRIER(t-1), and stage is issued after
// BARRIER(t-1). Reads(t+1) start only after BARRIER(t), which follows
// every wave's own VMCNT(0) covering its stage loads. No timing holes.
// Swizzle (64B rows): chunk ^= (row>>1)&3 -> slots 0,4,1,5,2,6,3,7
// per 8 rows = exact 2-way (free). Source-side same XOR (involution).
// =====================================================================

#define KLOOP(NT, STRIDE) do { \
  { /* prologue: tile 0 */ \
    bf16* D_ = smem; \
    gload16(srcA0, D_ + tid8); \
    gload16(srcB0, D_ + 4096 + tid8); \
    gload16(srcB1, D_ + 8192 + tid8); \
    VMCNT0(); \
    BARRIER(); \
  } \
  for (int t = 0; t < (NT); ++t) { \
    const bf16* buf = smem + (t & 1) * 12288; \
    bf16x8 aA[4], aB[4]; \
    _Pragma("unroll") for (int i = 0; i < 4; ++i) { \
      const int ra = wr * 64 + i * 16 + fr; \
      aA[i] = *(const bf16x8*)(buf + ra * 32 + ((k4 ^ ((ra >> 1) & 3)) << 3)); \
    } \
    _Pragma("unroll") for (int j = 0; j < 4; ++j) { \
      const int rb = wc * 64 + j * 16 + fr; \
      aB[j] = *(const bf16x8*)(buf + 4096 + rb * 32 + ((k4 ^ ((rb >> 1) & 3)) << 3)); \
    } \
    if (t + 1 < (NT)) { \
      bf16* D_ = smem + ((t + 1) & 1) * 12288; \
      const int ko = (t + 1) * 32; \
      gload16(srcA0 + ko, D_ + tid8); \
      gload16(srcB0 + ko, D_ + 4096 + tid8); \
      gload16(srcB1 + ko, D_ + 8192 + tid8); \
    } \
    PRIO1(); \
    _Pragma("unroll") for (int i = 0; i < 4; ++i) \
      _Pragma("unroll") for (int j = 0; j < 4; ++j) \
        acc[i][j] = __builtin_amdgcn_mfma_f32_16x16x32_bf16(aA[i], aB[j], acc[i][j], 0, 0, 0); \
    PRIO0(); \
    VMCNT0(); \
    BARRIER(); \
  } \
} while (0)

// ---------------- FFN up GEMM: h = gelu(A @ W1^T + b1) ----------------
__global__ __launch_bounds__(512, 4) void ffn1_gemm(const bf16* __restrict__ xb,
                                                    const bf16* __restrict__ w1t,
                                                    const float* __restrict__ bias1,
                                                    const int* __restrict__ sel,
                                                    bf16* __restrict__ hout,
                                                    int routed) {
  const int e = blockIdx.z;
  const bf16* Bw = w1t + (routed ? (size_t)e * HFFN * DMODEL : 0);
  const float* bias = bias1 + (routed ? (size_t)e * HFFN : 0);
  bf16* hb = hout + (routed ? (size_t)e * CAP * HFFN : 0);
  int bx, by;
  xcd_remap(bx, by);
  const int m0 = by * 128, n0 = bx * 256;
  __shared__ __align__(16) bf16 smem[24576];   // 48 KiB: 2 x (A 128x32 | B 256x32)
  const int tid = threadIdx.x, lane = tid & 63, wave = tid >> 6;
  const int wr = wave >> 2, wc = wave & 3;
  const int tid8 = tid * 8;
  const int fr = lane & 15, k4 = lane >> 4;

  const int srow = tid >> 2, sch = tid & 3;
  const int schs = sch ^ ((srow >> 1) & 3);
  const bf16 *srcA0, *srcB0, *srcB1;
  {
    int ra = routed ? sel[e * CAP + m0 + srow] : (m0 + srow);
    srcA0 = xb + (size_t)ra * DMODEL + schs * 8;
    srcB0 = Bw + (size_t)(n0 + srow) * DMODEL + schs * 8;
    srcB1 = Bw + (size_t)(n0 + 128 + srow) * DMODEL + schs * 8;
  }

  f32x4 acc[4][4];
  #pragma unroll
  for (int i = 0; i < 4; ++i)
    #pragma unroll
    for (int j = 0; j < 4; ++j) acc[i][j] = (f32x4){0.f, 0.f, 0.f, 0.f};

  KLOOP(DMODEL / 32, DMODEL);

  // epilogue: bias+gelu -> bf16; bounce 128x128 col-halves through smem
  __syncthreads();
  #pragma unroll
  for (int half = 0; half < 2; ++half) {
    if ((wc >> 1) == half) {
      #pragma unroll
      for (int i = 0; i < 4; ++i) {
        #pragma unroll
        for (int j = 0; j < 4; ++j) {
          const int cl = (wc & 1) * 64 + j * 16 + fr;
          const float bb = bias[n0 + half * 128 + cl];
          #pragma unroll
          for (int q = 0; q < 4; ++q) {
            const int ml = wr * 64 + i * 16 + k4 * 4 + q;
            smem[ml * 128 + (cl ^ (((ml >> 2) & 7) << 4))] =
                (bf16)gelu_f(acc[i][j][q] + bb);
          }
        }
      }
    }
    __syncthreads();
    #pragma unroll
    for (int p = 0; p < 4; ++p) {
      const int f = p * 512 + tid;
      const int row = f >> 4, c8 = f & 15;
      uint4 v = *(const uint4*)(smem + row * 128 + ((c8 * 8) ^ (((row >> 2) & 7) << 4)));
      *(uint4*)(hb + (size_t)(m0 + row) * HFFN + n0 + half * 128 + c8 * 8) = v;
    }
    __syncthreads();
  }
}

// ---------------- FFN down GEMM: y = h @ W2^T + b2 ----------------
__global__ __launch_bounds__(512, 4) void ffn2_gemm(const bf16* __restrict__ hbuf,
                                                    const bf16* __restrict__ w2t,
                                                    const float* __restrict__ bias2,
                                                    const int* __restrict__ sel,
                                                    const float* __restrict__ scr,
                                                    float* __restrict__ out,
                                                    int routed) {
  const int e = blockIdx.z;
  const bf16* Ab = hbuf + (routed ? (size_t)e * CAP * HFFN : 0);
  const bf16* Bw = w2t + (routed ? (size_t)e * DMODEL * HFFN : 0);
  const float* bias = bias2 + (routed ? (size_t)e * DMODEL : 0);
  int bx, by;
  xcd_remap(bx, by);
  const int m0 = by * 128, n0 = bx * 256;
  __shared__ __align__(16) bf16 smem[24576];
  __shared__ int s_tok[128];
  __shared__ float s_scl[128];
  const int tid = threadIdx.x, lane = tid & 63, wave = tid >> 6;
  const int wr = wave >> 2, wc = wave & 3;
  const int tid8 = tid * 8;
  const int fr = lane & 15, k4 = lane >> 4;

  const int srow = tid >> 2, sch = tid & 3;
  const int schs = sch ^ ((srow >> 1) & 3);
  const bf16* srcA0 = Ab + (size_t)(m0 + srow) * HFFN + schs * 8;
  const bf16* srcB0 = Bw + (size_t)(n0 + srow) * HFFN + schs * 8;
  const bf16* srcB1 = Bw + (size_t)(n0 + 128 + srow) * HFFN + schs * 8;
  if (routed && tid < 128) {
    s_tok[tid] = sel[e * CAP + m0 + tid];
    s_scl[tid] = scr[e * CAP + m0 + tid];
  }

  f32x4 acc[4][4];
  #pragma unroll
  for (int i = 0; i < 4; ++i)
    #pragma unroll
    for (int j = 0; j < 4; ++j) acc[i][j] = (f32x4){0.f, 0.f, 0.f, 0.f};

  KLOOP(HFFN / 32, HFFN);

  if (!routed) {
    #pragma unroll
    for (int i = 0; i < 4; ++i) {
      #pragma unroll
      for (int j = 0; j < 4; ++j) {
        const int nl = wc * 64 + j * 16 + fr;
        const float bb = bias[n0 + nl];
        #pragma unroll
        for (int q = 0; q < 4; ++q) {
          const int ml = wr * 64 + i * 16 + k4 * 4 + q;
          out[(size_t)(m0 + ml) * DMODEL + n0 + nl] = acc[i][j][q] + bb;
        }
      }
    }
  } else {
    __syncthreads();
    #pragma unroll
    for (int i = 0; i < 4; ++i) {
      #pragma unroll
      for (int j = 0; j < 4; ++j) {
        const int nl = wc * 64 + j * 16 + fr;
        const float bb = bias[n0 + nl];
        #pragma unroll
        for (int q = 0; q < 4; ++q) {
          const int ml = wr * 64 + i * 16 + k4 * 4 + q;
          const int tok = s_tok[ml];
          const float sc = s_scl[ml];
          atomicAdd(out + (size_t)tok * DMODEL + n0 + nl, (acc[i][j][q] + bb) * sc);
        }
      }
    }
  }
}

extern "C" void kernel_launch(void* const* d_in, const int* in_sizes, int n_in,
                              void* d_out, int out_size, void* d_ws, size_t ws_size,
                              hipStream_t stream) {
  const float* x   = (const float*)d_in[0];
  const float* gw  = (const float*)d_in[1];
  const float* ew1 = (const float*)d_in[2];
  const float* eb1 = (const float*)d_in[3];
  const float* ew2 = (const float*)d_in[4];
  const float* eb2 = (const float*)d_in[5];
  const float* sw1 = (const float*)d_in[6];
  const float* sb1 = (const float*)d_in[7];
  const float* sw2 = (const float*)d_in[8];
  const float* sb2 = (const float*)d_in[9];
  float* out = (float*)d_out;

  char* ws = (char*)d_ws;
  size_t off = 0;
  bf16* xb      = (bf16*)(ws + off); off += (size_t)NTOK * DMODEL * 2;
  bf16* w1t     = (bf16*)(ws + off); off += (size_t)9 * HFFN * DMODEL * 2;
  bf16* w2t     = (bf16*)(ws + off); off += (size_t)9 * DMODEL * HFFN * 2;
  bf16* hbuf    = (bf16*)(ws + off); off += (size_t)NTOK * HFFN * 2;
  float* probs  = (float*)(ws + off); off += (size_t)NEXP * NTOK * 4;
  int* selidx   = (int*)(ws + off);   off += (size_t)NEXP * CAP * 4;
  float* selscr = (float*)(ws + off); off += (size_t)NEXP * CAP * 4;

  cvt_x_kernel<<<dim3(NTOK * DMODEL / 8 / 256), dim3(256), 0, stream>>>(x, xb);
  router_kernel<<<dim3(NTOK), dim3(64), 0, stream>>>(x, gw, probs);
  topk_kernel<<<dim3(NEXP), dim3(256), 0, stream>>>(probs, selidx, selscr);
  transpose_cvt<<<dim3(HFFN / 64, DMODEL / 64, 9), dim3(256), 0, stream>>>(ew1, sw1, w1t, DMODEL, HFFN);
  transpose_cvt<<<dim3(DMODEL / 64, HFFN / 64, 9), dim3(256), 0, stream>>>(ew2, sw2, w2t, HFFN, DMODEL);

  ffn1_gemm<<<dim3(HFFN / 256, NTOK / 128, 1), dim3(512), 0, stream>>>(
      xb, w1t + (size_t)8 * HFFN * DMODEL, sb1, (const int*)nullptr, hbuf, 0);
  ffn2_gemm<<<dim3(DMODEL / 256, NTOK / 128, 1), dim3(512), 0, stream>>>(
      hbuf, w2t + (size_t)8 * DMODEL * HFFN, sb2, (const int*)nullptr, (const float*)nullptr, out, 0);

  ffn1_gemm<<<dim3(HFFN / 256, CAP / 128, NEXP), dim3(512), 0, stream>>>(
      xb, w1t, eb1, selidx, hbuf, 1);
  ffn2_gemm<<<dim3(DMODEL / 256, CAP / 128, NEXP), dim3(512), 0, stream>>>(
      hbuf, w2t, eb2, selidx, selscr, out, 1);
}

// Round 12
// 835.840 us; speedup vs baseline: 1.0977x; 1.0977x over previous
//
#include <hip/hip_runtime.h>

typedef __bf16 bf16;
typedef __bf16 bf16x8 __attribute__((ext_vector_type(8)));
typedef float f32x4 __attribute__((ext_vector_type(4)));

#define NTOK 16384
#define DMODEL 1024
#define HFFN 4096
#define NEXP 8
#define CAP 2048

#define VMCNT(n) asm volatile("s_waitcnt vmcnt(" #n ")" ::: "memory")
#define BARRIER() __builtin_amdgcn_s_barrier()
#define PRIO1() __builtin_amdgcn_s_setprio(1)
#define PRIO0() __builtin_amdgcn_s_setprio(0)

__device__ __forceinline__ void gload16(const void* g, void* l) {
  __builtin_amdgcn_global_load_lds((const __attribute__((address_space(1))) void*)g,
                                   (__attribute__((address_space(3))) void*)l, 16, 0, 0);
}

// exact tanh-approx gelu via sigmoid identity
__device__ __forceinline__ float gelu_f(float v) {
  float t = v * v;
  float s2 = v * fmaf(0.10294358f, t, 2.3022084f);
  float e = __builtin_exp2f(-s2);
  return v * __builtin_amdgcn_rcpf(1.0f + e);
}

__device__ __forceinline__ void xcd_remap(int& bx, int& by) {
  const int gx = gridDim.x;
  const int lg = 31 - __clz((unsigned)gx);
  const int w = blockIdx.x + gx * blockIdx.y;
  bx = (w >> 3) & (gx - 1);
  by = (w & 7) | (((w >> 3) >> lg) << 3);
}

// ---------------- x: f32 -> bf16 ----------------
__global__ __launch_bounds__(256) void cvt_x_kernel(const float* __restrict__ x,
                                                    bf16* __restrict__ xb) {
  int i = blockIdx.x * blockDim.x + threadIdx.x;
  const float4* a = (const float4*)x + (size_t)i * 2;
  float4 v0 = a[0], v1 = a[1];
  bf16x8 o;
  o[0]=(bf16)v0.x; o[1]=(bf16)v0.y; o[2]=(bf16)v0.z; o[3]=(bf16)v0.w;
  o[4]=(bf16)v1.x; o[5]=(bf16)v1.y; o[6]=(bf16)v1.z; o[7]=(bf16)v1.w;
  *(bf16x8*)(xb + (size_t)i * 8) = o;
}

// ---------------- router ----------------
__global__ __launch_bounds__(64) void router_kernel(const float* __restrict__ x,
                                                    const float* __restrict__ gw,
                                                    float* __restrict__ probs) {
  int t = blockIdx.x;
  int l = threadIdx.x;
  int e = l & 7, chunk = l >> 3;
  const float* xr = x + (size_t)t * DMODEL + chunk * 128;
  const float* gwr = gw + (size_t)(chunk * 128) * NEXP + e;
  float a0 = 0.f, a1 = 0.f;
  #pragma unroll
  for (int d = 0; d < 128; d += 8) {
    float4 xv = *(const float4*)(xr + d);
    float4 xw = *(const float4*)(xr + d + 4);
    a0 += xv.x * gwr[(d+0)*8] + xv.y * gwr[(d+1)*8] + xv.z * gwr[(d+2)*8] + xv.w * gwr[(d+3)*8];
    a1 += xw.x * gwr[(d+4)*8] + xw.y * gwr[(d+5)*8] + xw.z * gwr[(d+6)*8] + xw.w * gwr[(d+7)*8];
  }
  float acc = a0 + a1;
  acc += __shfl_xor(acc, 8);
  acc += __shfl_xor(acc, 16);
  acc += __shfl_xor(acc, 32);
  float m = acc;
  m = fmaxf(m, __shfl_xor(m, 1));
  m = fmaxf(m, __shfl_xor(m, 2));
  m = fmaxf(m, __shfl_xor(m, 4));
  float ex = expf(acc - m);
  float s = ex;
  s += __shfl_xor(s, 1); s += __shfl_xor(s, 2); s += __shfl_xor(s, 4);
  if (l < 8) probs[(size_t)e * NTOK + t] = ex / s;
}

// ---------------- per-expert top-2048 radix select ----------------
__global__ __launch_bounds__(256) void topk_kernel(const float* __restrict__ probs,
                                                   int* __restrict__ oidx,
                                                   float* __restrict__ oscr) {
  const int e = blockIdx.x;
  const float* p = probs + (size_t)e * NTOK;
  const int t = threadIdx.x;
  __shared__ unsigned hist[256];
  __shared__ unsigned sg[256], sq[256];
  __shared__ unsigned bcast[4];
  unsigned pref = 0, krem = CAP;
  for (int pass = 0; pass < 4; ++pass) {
    const int sh = 24 - pass * 8;
    hist[t] = 0;
    __syncthreads();
    for (int j = 0; j < 64; ++j) {
      unsigned u = __float_as_uint(p[t * 64 + j]);
      bool ok = (pass == 0) || ((u >> (sh + 8)) == pref);
      if (ok) atomicAdd(&hist[(u >> sh) & 255u], 1u);
    }
    __syncthreads();
    if (t == 0) {
      unsigned cum = 0; int b = 255;
      for (; b > 0; --b) {
        unsigned c = hist[b];
        if (cum + c >= krem) break;
        cum += c;
      }
      bcast[0] = (pref << 8) | (unsigned)b;
      bcast[1] = krem - cum;
    }
    __syncthreads();
    pref = bcast[0];
    krem = bcast[1];
  }
  const unsigned thr = pref;
  const unsigned neq_take = krem;
  unsigned cgt = 0, ceq = 0;
  for (int j = 0; j < 64; ++j) {
    unsigned u = __float_as_uint(p[t * 64 + j]);
    cgt += (u > thr);
    ceq += (u == thr);
  }
  sg[t] = cgt; sq[t] = ceq;
  __syncthreads();
  if (t == 0) {
    unsigned ag = 0, aq = 0;
    for (int i = 0; i < 256; ++i) {
      unsigned g = sg[i], q = sq[i];
      sg[i] = ag; sq[i] = aq;
      ag += g; aq += q;
    }
    bcast[2] = ag;
  }
  __syncthreads();
  const unsigned ngt = bcast[2];
  unsigned og = sg[t], oq = sq[t];
  int* oi = oidx + e * CAP;
  float* os = oscr + e * CAP;
  for (int j = 0; j < 64; ++j) {
    int tok = t * 64 + j;
    float pv = p[tok];
    unsigned u = __float_as_uint(pv);
    if (u > thr) {
      oi[og] = tok; os[og] = pv; ++og;
    } else if (u == thr) {
      if (oq < neq_take) { oi[ngt + oq] = tok; os[ngt + oq] = pv; }
      ++oq;
    }
  }
}

// ---------------- weight transpose + cvt ----------------
__global__ __launch_bounds__(256) void transpose_cvt(const float* __restrict__ in_e,
                                                     const float* __restrict__ in_s,
                                                     bf16* __restrict__ outp,
                                                     int R, int C) {
  int z = blockIdx.z;
  const float* in = (z < 8) ? (in_e + (size_t)z * (size_t)R * C) : in_s;
  bf16* out = outp + (size_t)z * (size_t)R * C;
  __shared__ float tile[64][65];
  int tx = threadIdx.x & 63, ty = threadIdx.x >> 6;
  int c0 = blockIdx.x * 64, r0 = blockIdx.y * 64;
  #pragma unroll
  for (int j = 0; j < 16; ++j) {
    int r = ty + j * 4;
    tile[r][tx] = in[(size_t)(r0 + r) * C + c0 + tx];
  }
  __syncthreads();
  #pragma unroll
  for (int j = 0; j < 16; ++j) {
    int c = ty + j * 4;
    out[(size_t)(c0 + c) * R + r0 + tx] = (bf16)tile[tx][c];
  }
}

// =====================================================================
// 256x256 tile, BK=64, 512 thr, 2 LDS buffers, 3 barriers / K-tile.
//   P0: read cur.{Alo,Blo,Bhi} (16 b128; Bhi's 4 retire under q00 via
//       compiler lgkmcnt); stage nxt.Ahi(t+1); BAR1; q00+q01 (32 MFMA).
//   P1: read cur.Ahi (8); BAR2 (anti-dependency barrier).
//   P2: stage cur.{Alo,Blo,Bhi}(t+2); q10+q11 (32 MFMA); VMCNT(6); BAR3.
// Region safety (drain-point discipline): readers of cur.{Alo,Blo,Bhi}
// drain at their q00/q01 MFMAs (pre-BAR2) -> stage after BAR2 is safe.
// nxt.Ahi last read at iter t-1 P1, drained pre-BAR3(t-1) -> P0 stage
// safe. Gate ledger: outstanding at gate = prevP2 6 + thisP0 2 +
// thisP2 6 = 14; VMCNT(6) retires exactly tile t+1's 8; all loads get
// ~a full iteration in flight. Tail: st2=false -> VMCNT(0) drains.
// =====================================================================

#define STG_ALO(D, ko) { gload16(srcA0 + (ko), (D) + tid8); gload16(srcA2 + (ko), (D) + 4096 + tid8); }
#define STG_AHI(D, ko) { gload16(srcA1 + (ko), (D) + 8192 + tid8); gload16(srcA3 + (ko), (D) + 12288 + tid8); }
#define STG_BLO(D, ko) { gload16(srcBlo0 + (ko), (D) + 16384 + tid8); gload16(srcBlo1 + (ko), (D) + 20480 + tid8); }
#define STG_BHI(D, ko) { gload16(srcBhi0 + (ko), (D) + 24576 + tid8); gload16(srcBhi1 + (ko), (D) + 28672 + tid8); }

#define RD_A(ARR, D, OFF) \
  _Pragma("unroll") for (int i = 0; i < 4; ++i) { \
    ARR[2*i]   = *(const bf16x8*)((D) + (OFF) + (wr*64 + i*16 + fr)*64 + c0s); \
    ARR[2*i+1] = *(const bf16x8*)((D) + (OFF) + (wr*64 + i*16 + fr)*64 + c1s); \
  }
#define RD_B(ARR, D, OFF) \
  _Pragma("unroll") for (int j = 0; j < 2; ++j) { \
    ARR[2*j]   = *(const bf16x8*)((D) + (OFF) + (wc*32 + j*16 + fr)*64 + c0s); \
    ARR[2*j+1] = *(const bf16x8*)((D) + (OFF) + (wc*32 + j*16 + fr)*64 + c1s); \
  }

#define MFMA_Q(I0, J0, A, B) \
  _Pragma("unroll") for (int i = 0; i < 4; ++i) \
    _Pragma("unroll") for (int j = 0; j < 2; ++j) { \
      acc[(I0)+i][(J0)+j] = __builtin_amdgcn_mfma_f32_16x16x32_bf16((A)[2*i],   (B)[2*j],   acc[(I0)+i][(J0)+j], 0, 0, 0); \
      acc[(I0)+i][(J0)+j] = __builtin_amdgcn_mfma_f32_16x16x32_bf16((A)[2*i+1], (B)[2*j+1], acc[(I0)+i][(J0)+j], 0, 0, 0); \
    }

#define KLOOP(NT) do { \
  bf16* B0_ = smem; \
  bf16* B1_ = smem + 32768; \
  STG_ALO(B0_, 0); STG_AHI(B0_, 0); STG_BLO(B0_, 0); STG_BHI(B0_, 0); \
  STG_ALO(B1_, 64); STG_BLO(B1_, 64); STG_BHI(B1_, 64); \
  VMCNT(6); \
  BARRIER(); \
  for (int t = 0; t < (NT); ++t) { \
    bf16* cur = smem + ((t & 1) << 15); \
    bf16* nxt = smem + (((t + 1) & 1) << 15); \
    const int ko1 = (t + 1) * 64, ko2 = (t + 2) * 64; \
    const bool st1 = (t + 1) < (NT), st2 = (t + 2) < (NT); \
    bf16x8 aA[8], S1[4], S2[4]; \
    /* ---- P0 ---- */ \
    RD_A(aA, cur, 0); \
    RD_B(S1, cur, 16384); \
    RD_B(S2, cur, 24576); \
    if (st1) STG_AHI(nxt, ko1); \
    BARRIER(); \
    PRIO1(); MFMA_Q(0,0,aA,S1); MFMA_Q(0,2,aA,S2); PRIO0(); \
    /* ---- P1 ---- */ \
    RD_A(aA, cur, 8192); \
    BARRIER(); \
    /* ---- P2 ---- */ \
    if (st2) { STG_ALO(cur, ko2); STG_BLO(cur, ko2); STG_BHI(cur, ko2); } \
    PRIO1(); MFMA_Q(4,0,aA,S1); MFMA_Q(4,2,aA,S2); PRIO0(); \
    if (st2) { VMCNT(6); } else { VMCNT(0); } \
    BARRIER(); \
  } \
} while (0)

// ---------------- FFN up GEMM: h = gelu(A @ W1^T + b1) ----------------
__global__ __launch_bounds__(512, 2) void ffn1_gemm(const bf16* __restrict__ xb,
                                                    const bf16* __restrict__ w1t,
                                                    const float* __restrict__ bias1,
                                                    const int* __restrict__ sel,
                                                    bf16* __restrict__ hout,
                                                    int routed) {
  const int e = blockIdx.z;
  const bf16* Bw = w1t + (routed ? (size_t)e * HFFN * DMODEL : 0);
  const float* bias = bias1 + (routed ? (size_t)e * HFFN : 0);
  bf16* hb = hout + (routed ? (size_t)e * CAP * HFFN : 0);
  int bx, by;
  xcd_remap(bx, by);
  const int m0 = by * 256, n0 = bx * 256;
  __shared__ __align__(16) bf16 smem[65536];   // 128 KiB
  const int tid = threadIdx.x, lane = tid & 63, wave = tid >> 6;
  const int wr = wave >> 2, wc = wave & 3;
  const int tid8 = tid * 8;

  const int p = tid >> 3, sch = tid & 7;
  const int schs = sch ^ (p & 7);
  const int brow = p + (p & 32);
  const bf16 *srcA0, *srcA1, *srcA2, *srcA3, *srcBlo0, *srcBlo1, *srcBhi0, *srcBhi1;
  {
    int ra0 = routed ? sel[e * CAP + m0 + p]       : (m0 + p);
    int ra1 = routed ? sel[e * CAP + m0 + 64 + p]  : (m0 + 64 + p);
    int ra2 = routed ? sel[e * CAP + m0 + 128 + p] : (m0 + 128 + p);
    int ra3 = routed ? sel[e * CAP + m0 + 192 + p] : (m0 + 192 + p);
    srcA0 = xb + (size_t)ra0 * DMODEL + schs * 8;
    srcA1 = xb + (size_t)ra1 * DMODEL + schs * 8;
    srcA2 = xb + (size_t)ra2 * DMODEL + schs * 8;
    srcA3 = xb + (size_t)ra3 * DMODEL + schs * 8;
    srcBlo0 = Bw + (size_t)(n0 + brow) * DMODEL + schs * 8;
    srcBlo1 = srcBlo0 + (size_t)128 * DMODEL;
    srcBhi0 = srcBlo0 + (size_t)32 * DMODEL;
    srcBhi1 = srcBlo0 + (size_t)160 * DMODEL;
  }

  f32x4 acc[8][4];
  #pragma unroll
  for (int i = 0; i < 8; ++i)
    #pragma unroll
    for (int j = 0; j < 4; ++j) acc[i][j] = (f32x4){0.f, 0.f, 0.f, 0.f};

  const int fr = lane & 15;
  const int k8 = lane >> 4;
  const int sw = lane & 7;
  const int c0s = (k8 ^ sw) * 8;
  const int c1s = ((k8 + 4) ^ sw) * 8;

  KLOOP(DMODEL / 64);

  // epilogue: bias+gelu -> bf16, two 128-row halves via swizzled LDS bounce
  __syncthreads();
  #pragma unroll
  for (int half = 0; half < 2; ++half) {
    if (wr == half) {
      #pragma unroll
      for (int i = 0; i < 8; ++i) {
        #pragma unroll
        for (int j = 0; j < 4; ++j) {
          const int nl = wc * 64 + j * 16 + fr;
          const float bb = bias[n0 + nl];
          #pragma unroll
          for (int q = 0; q < 4; ++q) {
            const int ml = i * 16 + (lane >> 4) * 4 + q;
            smem[ml * 256 + (nl ^ (((ml >> 2) & 7) << 4))] =
                (bf16)gelu_f(acc[i][j][q] + bb);
          }
        }
      }
    }
    __syncthreads();
    #pragma unroll
    for (int pp = 0; pp < 8; ++pp) {
      const int flat = pp * 512 + tid;
      const int row = flat >> 5, nc8 = flat & 31;
      uint4 v = *(const uint4*)(smem + row * 256 + ((nc8 * 8) ^ (((row >> 2) & 7) << 4)));
      *(uint4*)(hb + (size_t)(m0 + half * 128 + row) * HFFN + n0 + nc8 * 8) = v;
    }
    __syncthreads();
  }
}

// ---------------- FFN down GEMM: y = h @ W2^T + b2 ----------------
__global__ __launch_bounds__(512, 2) void ffn2_gemm(const bf16* __restrict__ hbuf,
                                                    const bf16* __restrict__ w2t,
                                                    const float* __restrict__ bias2,
                                                    const int* __restrict__ sel,
                                                    const float* __restrict__ scr,
                                                    float* __restrict__ out,
                                                    int routed) {
  const int e = blockIdx.z;
  const bf16* Ab = hbuf + (routed ? (size_t)e * CAP * HFFN : 0);
  const bf16* Bw = w2t + (routed ? (size_t)e * DMODEL * HFFN : 0);
  const float* bias = bias2 + (routed ? (size_t)e * DMODEL : 0);
  int bx, by;
  xcd_remap(bx, by);
  const int m0 = by * 256, n0 = bx * 256;
  __shared__ __align__(16) bf16 smem[65536];
  __shared__ int s_tok[256];
  __shared__ float s_scl[256];
  const int tid = threadIdx.x, lane = tid & 63, wave = tid >> 6;
  const int wr = wave >> 2, wc = wave & 3;
  const int tid8 = tid * 8;

  const int p = tid >> 3, sch = tid & 7;
  const int schs = sch ^ (p & 7);
  const int brow = p + (p & 32);
  const bf16* srcA0 = Ab + (size_t)(m0 + p) * HFFN + schs * 8;
  const bf16* srcA1 = Ab + (size_t)(m0 + 64 + p) * HFFN + schs * 8;
  const bf16* srcA2 = Ab + (size_t)(m0 + 128 + p) * HFFN + schs * 8;
  const bf16* srcA3 = Ab + (size_t)(m0 + 192 + p) * HFFN + schs * 8;
  const bf16* srcBlo0 = Bw + (size_t)(n0 + brow) * HFFN + schs * 8;
  const bf16* srcBlo1 = srcBlo0 + (size_t)128 * HFFN;
  const bf16* srcBhi0 = srcBlo0 + (size_t)32 * HFFN;
  const bf16* srcBhi1 = srcBlo0 + (size_t)160 * HFFN;
  if (routed && tid < 256) {
    s_tok[tid] = sel[e * CAP + m0 + tid];
    s_scl[tid] = scr[e * CAP + m0 + tid];
  }

  f32x4 acc[8][4];
  #pragma unroll
  for (int i = 0; i < 8; ++i)
    #pragma unroll
    for (int j = 0; j < 4; ++j) acc[i][j] = (f32x4){0.f, 0.f, 0.f, 0.f};

  const int fr = lane & 15;
  const int k8 = lane >> 4;
  const int sw = lane & 7;
  const int c0s = (k8 ^ sw) * 8;
  const int c1s = ((k8 + 4) ^ sw) * 8;

  KLOOP(HFFN / 64);

  if (!routed) {
    #pragma unroll
    for (int i = 0; i < 8; ++i) {
      #pragma unroll
      for (int j = 0; j < 4; ++j) {
        const int nl = wc * 64 + j * 16 + fr;
        const float bb = bias[n0 + nl];
        #pragma unroll
        for (int q = 0; q < 4; ++q) {
          const int ml = wr * 128 + i * 16 + (lane >> 4) * 4 + q;
          out[(size_t)(m0 + ml) * DMODEL + n0 + nl] = acc[i][j][q] + bb;
        }
      }
    }
  } else {
    __syncthreads();
    #pragma unroll
    for (int i = 0; i < 8; ++i) {
      #pragma unroll
      for (int j = 0; j < 4; ++j) {
        const int nl = wc * 64 + j * 16 + fr;
        const float bb = bias[n0 + nl];
        #pragma unroll
        for (int q = 0; q < 4; ++q) {
          const int ml = wr * 128 + i * 16 + (lane >> 4) * 4 + q;
          const int tok = s_tok[ml];
          const float sc = s_scl[ml];
          atomicAdd(out + (size_t)tok * DMODEL + n0 + nl, (acc[i][j][q] + bb) * sc);
        }
      }
    }
  }
}

extern "C" void kernel_launch(void* const* d_in, const int* in_sizes, int n_in,
                              void* d_out, int out_size, void* d_ws, size_t ws_size,
                              hipStream_t stream) {
  const float* x   = (const float*)d_in[0];
  const float* gw  = (const float*)d_in[1];
  const float* ew1 = (const float*)d_in[2];
  const float* eb1 = (const float*)d_in[3];
  const float* ew2 = (const float*)d_in[4];
  const float* eb2 = (const float*)d_in[5];
  const float* sw1 = (const float*)d_in[6];
  const float* sb1 = (const float*)d_in[7];
  const float* sw2 = (const float*)d_in[8];
  const float* sb2 = (const float*)d_in[9];
  float* out = (float*)d_out;

  char* ws = (char*)d_ws;
  size_t off = 0;
  bf16* xb      = (bf16*)(ws + off); off += (size_t)NTOK * DMODEL * 2;
  bf16* w1t     = (bf16*)(ws + off); off += (size_t)9 * HFFN * DMODEL * 2;
  bf16* w2t     = (bf16*)(ws + off); off += (size_t)9 * DMODEL * HFFN * 2;
  bf16* hbuf    = (bf16*)(ws + off); off += (size_t)NTOK * HFFN * 2;
  float* probs  = (float*)(ws + off); off += (size_t)NEXP * NTOK * 4;
  int* selidx   = (int*)(ws + off);   off += (size_t)NEXP * CAP * 4;
  float* selscr = (float*)(ws + off); off += (size_t)NEXP * CAP * 4;

  cvt_x_kernel<<<dim3(NTOK * DMODEL / 8 / 256), dim3(256), 0, stream>>>(x, xb);
  router_kernel<<<dim3(NTOK), dim3(64), 0, stream>>>(x, gw, probs);
  topk_kernel<<<dim3(NEXP), dim3(256), 0, stream>>>(probs, selidx, selscr);
  transpose_cvt<<<dim3(HFFN / 64, DMODEL / 64, 9), dim3(256), 0, stream>>>(ew1, sw1, w1t, DMODEL, HFFN);
  transpose_cvt<<<dim3(DMODEL / 64, HFFN / 64, 9), dim3(256), 0, stream>>>(ew2, sw2, w2t, HFFN, DMODEL);

  ffn1_gemm<<<dim3(HFFN / 256, NTOK / 256, 1), dim3(512), 0, stream>>>(
      xb, w1t + (size_t)8 * HFFN * DMODEL, sb1, (const int*)nullptr, hbuf, 0);
  ffn2_gemm<<<dim3(DMODEL / 256, NTOK / 256, 1), dim3(512), 0, stream>>>(
      hbuf, w2t + (size_t)8 * DMODEL * HFFN, sb2, (const int*)nullptr, (const float*)nullptr, out, 0);

  ffn1_gemm<<<dim3(HFFN / 256, CAP / 256, NEXP), dim3(512), 0, stream>>>(
      xb, w1t, eb1, selidx, hbuf, 1);
  ffn2_gemm<<<dim3(DMODEL / 256, CAP / 256, NEXP), dim3(512), 0, stream>>>(
      hbuf, w2t, eb2, selidx, selscr, out, 1);
}